// Round 12
// baseline (476.944 us; speedup 1.0000x reference)
//
#include <hip/hip_runtime.h>

#define NTHREADS 512

typedef __attribute__((ext_vector_type(8))) short s16x8;
typedef __attribute__((ext_vector_type(4))) float f32x4;
typedef __attribute__((ext_vector_type(4))) unsigned int u32x4;

__device__ __forceinline__ unsigned short f2bf(float f) {
  unsigned u = __float_as_uint(f);
  u += 0x7fffu + ((u >> 16) & 1u);
  return (unsigned short)(u >> 16);
}
__device__ __forceinline__ float bf2f(unsigned short s) {
  return __uint_as_float(((unsigned)s) << 16);
}
__device__ __forceinline__ float sigm(float x) {
  return __builtin_amdgcn_rcpf(1.0f + __expf(-x));
}
__device__ __forceinline__ float tanh_fast(float x) {
  return 1.0f - 2.0f * __builtin_amdgcn_rcpf(1.0f + __expf(2.0f * x));
}
__device__ __forceinline__ f32x4 mfma_bf16(u32x4 a, u32x4 b, f32x4 c) {
  union { u32x4 u; s16x8 s; } ua, ub;
  ua.u = a; ub.u = b;
  return __builtin_amdgcn_mfma_f32_16x16x32_bf16(ua.s, ub.s, c, 0, 0, 0);
}

// ---------------- weight pre-pack (UNCHANGED layout) ----------------
// [nb(16)][kb][g(4)][16 n][8 k], bf16.
//   W0p: kb in [0,52)  (k = kb*8: k<160 from W_ih0, else W_hh0)
//   W1p: kb in [0,64)  (k<256 from W_ih1, else W_hh1)
// b0/b1: b_ih+b_hh pre-summed, f32.
__global__ void pack_weights(const float* __restrict__ Wih0, const float* __restrict__ Whh0,
                             const float* __restrict__ bih0, const float* __restrict__ bhh0,
                             const float* __restrict__ Wih1, const float* __restrict__ Whh1,
                             const float* __restrict__ bih1, const float* __restrict__ bhh1,
                             unsigned short* __restrict__ W0p, unsigned short* __restrict__ W1p,
                             float* __restrict__ b0, float* __restrict__ b1) {
  int e = blockIdx.x * 256 + threadIdx.x;
  const int N0 = 16 * 52 * 4 * 128;   // 425984
  const int N1 = 16 * 64 * 4 * 128;   // 524288
  if (e < N0) {
    int kk = e & 7, t1 = e >> 3;
    int n = t1 & 15, t2 = t1 >> 4;
    int g = t2 & 3, t3 = t2 >> 2;
    int kb = t3 % 52, nb = t3 / 52;
    int gn = g * 256 + nb * 16 + n, k = kb * 8 + kk;
    float v = (k < 160) ? Wih0[gn * 160 + k] : Whh0[gn * 256 + (k - 160)];
    W0p[e] = f2bf(v);
  } else if (e < N0 + N1) {
    int e2 = e - N0;
    int kk = e2 & 7, t1 = e2 >> 3;
    int n = t1 & 15, t2 = t1 >> 4;
    int g = t2 & 3, t3 = t2 >> 2;
    int kb = t3 & 63, nb = t3 >> 6;
    int gn = g * 256 + nb * 16 + n, k = kb * 8 + kk;
    float v = (k < 256) ? Wih1[gn * 256 + k] : Whh1[gn * 256 + (k - 256)];
    W1p[e2] = f2bf(v);
  } else if (e < N0 + N1 + 1024) {
    int n = e - (N0 + N1);
    b0[n] = bih0[n] + bhh0[n];
  } else if (e < N0 + N1 + 2048) {
    int n = e - (N0 + N1 + 1024);
    b1[n] = bih1[n] + bhh1[n];
  }
}

// ---- rolled K-pass, reordered W prefetch (r9, unchanged — RA-proven) ----
// REGISTER WALL (r3,r4,r5,r7,r10): staging must not cross any phase
// boundary; 2+2 slots / 64 staging regs is the proven envelope.
__device__ __forceinline__ void ld4(u32x4 d[4], const u32x4* p) {
  d[0] = p[0]; d[1] = p[16]; d[2] = p[32]; d[3] = p[48];
}
__device__ __forceinline__ void mfma16(const u32x4 a[4], const u32x4 b[4],
                                       f32x4 acc[4][4]) {
#pragma unroll
  for (int g = 0; g < 4; g++)
#pragma unroll
    for (int rt = 0; rt < 4; rt++)
      acc[g][rt] = mfma_bf16(a[rt], b[g], acc[g][rt]);
}
template <int N, int SW>
__device__ __forceinline__ void kloop2(const u32x4* apX, const u32x4* apH,
                                       const u32x4* wp, f32x4 acc[4][4]) {
  u32x4 a0[4], b0[4], a1[4], b1[4];
  const u32x4* ap = apX;
  ld4(a0, ap); ap += 256;
  ld4(b0, wp); ld4(b1, wp + 256); wp += 512;
  int g = 1;  // next A group index to load
#pragma unroll 1
  for (int i = 0; i < (N - 2 + (N & 1)) / 2; i++) {
    if (g == SW) ap = apH;
    ld4(a1, ap); ap += 256; g++;        // A for group 2i+1 (dist 1)
    mfma16(a0, b0, acc);                // consume group 2i
    ld4(b0, wp); wp += 256;             // W refill -> group 2i+2 (dist ~2.5)
    if (g == SW) ap = apH;
    ld4(a0, ap); ap += 256; g++;        // A for group 2i+2
    mfma16(a1, b1, acc);                // consume group 2i+1
    ld4(b1, wp); wp += 256;             // W refill -> group 2i+3
  }
  if constexpr ((N & 1) == 0) {
    if (g == SW) ap = apH;
    ld4(a1, ap);                        // A for group N-1
    mfma16(a0, b0, acc);                // group N-2
    mfma16(a1, b1, acc);                // group N-1
  } else {
    mfma16(a0, b0, acc);                // group N-1
  }
}

// ---------------- fused 2-layer LSTM + FC (wave-specialized) ----------------
// Round 19: producer/consumer layer split. Waves 0-3 (group A) compute L0,
// waves 4-7 (group B) compute L1, pipelined ONE step apart:
//   superstep s: [stage x(s)] barrier; A: FC(s-2) + L0(s) || B: L1(s-1); barrier.
// Each SIMD hosts 1 A-wave + 1 B-wave running DIFFERENT code -> stalls
// decorrelate (r3's goal without the tile-halving L2 cost). Inter-barrier
// runs grow to 52/64 k-groups. Register wall RELAXED: each wave holds only
// its own layer's c-state (64 floats, 4 jt x 16, rotated 4-slot) instead
// of both layers' 128. Same 64-reg transient staging, same rolled kloop2,
// same LDS map. Barriers are in uniform control flow (none inside the
// wave-divergent region). Dbuf parity: group-local t, rd=t&1, wr=rd^1
// (unchanged math); FC(t) reads h2[(t&1)^1] two supersteps after B wrote
// it, always the opposite buffer from B's concurrent write.
__global__ __attribute__((amdgpu_flat_work_group_size(NTHREADS, NTHREADS),
                          amdgpu_waves_per_eu(2, 2)))
void lstm_fused(const float* __restrict__ x,
                const unsigned short* __restrict__ W0p,
                const unsigned short* __restrict__ W1p,
                const float* __restrict__ b0,
                const float* __restrict__ b1,
                const float* __restrict__ Wfc,
                const float* __restrict__ bfc,
                float* __restrict__ out) {
  __shared__ unsigned int lds_x[20 * 64 * 4];   // 20480 B
  __shared__ unsigned int lds_h1[16384];        // 65536 B = 2 bufs x [32 kblk][64 row][8k]
  __shared__ unsigned int lds_h2[16384];        // 65536 B
  __shared__ float lds_red[512];                // 2048 B (256 used + reduce)
  __shared__ float lds_b0[1024];                // 4096 B
  __shared__ float lds_b1[1024];                // 4096 B   total 161792 B

  const int tid = threadIdx.x;
  const int wave = tid >> 6;
  const int lane = tid & 63;
  const int l15 = lane & 15;
  const int quad = lane >> 4;
  const long rowg0 = (long)blockIdx.x * 64;
  const bool isA = (wave < 4);
  const int wg = isA ? wave : (wave - 4);   // group-local wave id

  for (int i = tid; i < 16384; i += NTHREADS) { lds_h1[i] = 0u; lds_h2[i] = 0u; }
  for (int i = tid; i < 1024; i += NTHREADS) { lds_b0[i] = b0[i]; lds_b1[i] = b1[i]; }

  // per-wave c-state: 4 jt slots as 4 named arrays (static indices),
  // rotated by one each jt iteration; cA = current jt. A-waves: layer-0
  // cell state; B-waves: layer-1. 64 floats/wave (was 128).
  float cA[4][4], cB[4][4], cC[4][4], cD[4][4];
#pragma unroll
  for (int rt = 0; rt < 4; rt++)
#pragma unroll
    for (int r = 0; r < 4; r++) {
      cA[rt][r] = 0.f; cB[rt][r] = 0.f; cC[rt][r] = 0.f; cD[rt][r] = 0.f;
    }
  float fc_acc = 0.0f;

  const u32x4* lxs = (const u32x4*)lds_x;
  const u32x4* lh1 = (const u32x4*)lds_h1;
  const u32x4* lh2 = (const u32x4*)lds_h2;
  unsigned short* lh1s = (unsigned short*)lds_h1;
  unsigned short* lh2s = (unsigned short*)lds_h2;
  const u32x4* w0q = (const u32x4*)W0p;
  const u32x4* w1q = (const u32x4*)W1p;

#pragma unroll 1
  for (int s = 0; s <= 10; s++) {
    // ---- stage x(s) -> lds_x (all waves; lds_x free after prev barrier) ----
    if (s < 10) {
#pragma unroll
      for (int st = 0; st < 5; st++) {
        int p = tid + st * NTHREADS;       // 2560 f32x4 = 64 rows x 40 quads
        int row = p / 40;
        int kq = p - row * 40;
        const f32x4 v = __builtin_nontemporal_load(
            (const f32x4*)(x + (rowg0 + row) * 1600 + s * 160 + kq * 4));
        unsigned lo = (unsigned)f2bf(v[0]) | ((unsigned)f2bf(v[1]) << 16);
        unsigned hi = (unsigned)f2bf(v[2]) | ((unsigned)f2bf(v[3]) << 16);
        int base = (kq >> 1) * 256 + row * 4 + (kq & 1) * 2;
        lds_x[base] = lo;
        lds_x[base + 1] = hi;
      }
    }
    __syncthreads();  // SB1: x(s) staged; prev superstep's h1/h2 visible

    if (isA) {
      // ---- FC(s-2): logit partial from h2(s-2) (stable buffer) ----
      if (s >= 2) {
        const int tfc = s - 2;
        const int buf = (tfc & 1) ^ 1;
        const int row = tid >> 2;          // tid in [0,256)
        const int slot = tid & 3;
        float sum = 0.f;
#pragma unroll
        for (int kb = 0; kb < 8; kb++) {
          u32x4 hv = lh2[buf * 2048 + (slot * 8 + kb) * 64 + row];
          const f32x4 wA = *(const f32x4*)(Wfc + tfc * 256 + slot * 64 + kb * 8);
          const f32x4 wB2 = *(const f32x4*)(Wfc + tfc * 256 + slot * 64 + kb * 8 + 4);
#pragma unroll
          for (int e = 0; e < 2; e++) {
            unsigned u = hv[e];
            sum += bf2f((unsigned short)(u & 0xffffu)) * wA[2 * e];
            sum += bf2f((unsigned short)(u >> 16)) * wA[2 * e + 1];
          }
#pragma unroll
          for (int e = 0; e < 2; e++) {
            unsigned u = hv[2 + e];
            sum += bf2f((unsigned short)(u & 0xffffu)) * wB2[2 * e];
            sum += bf2f((unsigned short)(u >> 16)) * wB2[2 * e + 1];
          }
        }
        fc_acc += sum;
      }
      // ---- L0(s): K=416 ([x_s | h1_prev]), 13 groups, switch@5 ----
      if (s < 10) {
        const int rd = s & 1, wr = rd ^ 1;
#pragma unroll 1
        for (int jt = 0; jt < 4; jt++) {
          const int nbb = wg * 4 + jt;
          f32x4 acc[4][4];
#pragma unroll
          for (int g = 0; g < 4; g++)
#pragma unroll
            for (int rt = 0; rt < 4; rt++) acc[g][rt] = (f32x4){0.f, 0.f, 0.f, 0.f};

          kloop2<13, 5>(lxs + quad * 64 + l15,
                        lh1 + rd * 2048 + quad * 64 + l15,
                        w0q + (nbb * 52 + quad) * 64 + l15, acc);

          const int col = nbb * 16 + l15;
          float b_i = lds_b0[0 * 256 + col];
          float b_f = lds_b0[1 * 256 + col];
          float b_g = lds_b0[2 * 256 + col];
          float b_o = lds_b0[3 * 256 + col];
#pragma unroll
          for (int rt = 0; rt < 4; rt++)
#pragma unroll
            for (int r = 0; r < 4; r++) {
              float iv = sigm(acc[0][rt][r] + b_i);
              float fv = sigm(acc[1][rt][r] + b_f);
              float gv = tanh_fast(acc[2][rt][r] + b_g);
              float ov = sigm(acc[3][rt][r] + b_o);
              float cn = fv * cA[rt][r] + iv * gv;
              cA[rt][r] = cn;
              int row = rt * 16 + quad * 4 + r;
              lh1s[wr * 16384 + ((col >> 3) * 64 + row) * 8 + (col & 7)] =
                  f2bf(ov * tanh_fast(cn));
            }
          // rotate c slots: (cA,cB,cC,cD) <- (cB,cC,cD,cA)
#pragma unroll
          for (int rt = 0; rt < 4; rt++)
#pragma unroll
            for (int r = 0; r < 4; r++) {
              float tmp = cA[rt][r];
              cA[rt][r] = cB[rt][r];
              cB[rt][r] = cC[rt][r];
              cC[rt][r] = cD[rt][r];
              cD[rt][r] = tmp;
            }
        }
      }
    } else {
      // ---- L1(s-1): K=512 ([h1_new | h2_prev]), 16 groups, switch@8 ----
      if (s >= 1) {
        const int tb = s - 1;
        const int rd = tb & 1, wr = rd ^ 1;
#pragma unroll 1
        for (int jt = 0; jt < 4; jt++) {
          const int nbb = wg * 4 + jt;
          f32x4 acc[4][4];
#pragma unroll
          for (int g = 0; g < 4; g++)
#pragma unroll
            for (int rt = 0; rt < 4; rt++) acc[g][rt] = (f32x4){0.f, 0.f, 0.f, 0.f};

          kloop2<16, 8>(lh1 + wr * 2048 + quad * 64 + l15,   // h1_new(tb)
                        lh2 + rd * 2048 + quad * 64 + l15,   // h2_prev
                        w1q + (nbb * 64 + quad) * 64 + l15, acc);

          const int col = nbb * 16 + l15;
          float b_i = lds_b1[0 * 256 + col];
          float b_f = lds_b1[1 * 256 + col];
          float b_g = lds_b1[2 * 256 + col];
          float b_o = lds_b1[3 * 256 + col];
#pragma unroll
          for (int rt = 0; rt < 4; rt++)
#pragma unroll
            for (int r = 0; r < 4; r++) {
              float iv = sigm(acc[0][rt][r] + b_i);
              float fv = sigm(acc[1][rt][r] + b_f);
              float gv = tanh_fast(acc[2][rt][r] + b_g);
              float ov = sigm(acc[3][rt][r] + b_o);
              float cn = fv * cA[rt][r] + iv * gv;
              cA[rt][r] = cn;
              int row = rt * 16 + quad * 4 + r;
              lh2s[wr * 16384 + ((col >> 3) * 64 + row) * 8 + (col & 7)] =
                  f2bf(ov * tanh_fast(cn));
            }
          // rotate c slots
#pragma unroll
          for (int rt = 0; rt < 4; rt++)
#pragma unroll
            for (int r = 0; r < 4; r++) {
              float tmp = cA[rt][r];
              cA[rt][r] = cB[rt][r];
              cB[rt][r] = cC[rt][r];
              cC[rt][r] = cD[rt][r];
              cD[rt][r] = tmp;
            }
        }
      }
    }
    __syncthreads();  // SB2: superstep complete
  }

  // ---- FC(9): h2(9) in buffer (9&1)^1 = 0, written at superstep 10 ----
  if (tid < 256) {
    const int tfc = 9;
    const int row = tid >> 2;
    const int slot = tid & 3;
    float sum = 0.f;
#pragma unroll
    for (int kb = 0; kb < 8; kb++) {
      u32x4 hv = lh2[0 * 2048 + (slot * 8 + kb) * 64 + row];
      const f32x4 wA = *(const f32x4*)(Wfc + tfc * 256 + slot * 64 + kb * 8);
      const f32x4 wB2 = *(const f32x4*)(Wfc + tfc * 256 + slot * 64 + kb * 8 + 4);
#pragma unroll
      for (int e = 0; e < 2; e++) {
        unsigned u = hv[e];
        sum += bf2f((unsigned short)(u & 0xffffu)) * wA[2 * e];
        sum += bf2f((unsigned short)(u >> 16)) * wA[2 * e + 1];
      }
#pragma unroll
      for (int e = 0; e < 2; e++) {
        unsigned u = hv[2 + e];
        sum += bf2f((unsigned short)(u & 0xffffu)) * wB2[2 * e];
        sum += bf2f((unsigned short)(u >> 16)) * wB2[2 * e + 1];
      }
    }
    fc_acc += sum;
    lds_red[tid] = fc_acc;   // [row(64)][slot(4)]
  }
  __syncthreads();
  if (tid < 64) {
    float s = 0.f;
#pragma unroll
    for (int e = 0; e < 4; e++) s += lds_red[tid * 4 + e];
    out[rowg0 + tid] = sigm(s + bfc[0]);
  }
}

extern "C" void kernel_launch(void* const* d_in, const int* in_sizes, int n_in,
                              void* d_out, int out_size, void* d_ws, size_t ws_size,
                              hipStream_t stream) {
  const float* x    = (const float*)d_in[0];
  const float* Wih0 = (const float*)d_in[1];
  const float* Whh0 = (const float*)d_in[2];
  const float* bih0 = (const float*)d_in[3];
  const float* bhh0 = (const float*)d_in[4];
  const float* Wih1 = (const float*)d_in[5];
  const float* Whh1 = (const float*)d_in[6];
  const float* bih1 = (const float*)d_in[7];
  const float* bhh1 = (const float*)d_in[8];
  const float* Wfc  = (const float*)d_in[9];
  const float* bfc  = (const float*)d_in[10];
  float* out = (float*)d_out;

  unsigned short* W0p = (unsigned short*)d_ws;         // 425984 bf16
  unsigned short* W1p = W0p + 16 * 52 * 4 * 128;       // 524288 bf16
  float* b0 = (float*)(W1p + 16 * 64 * 4 * 128);       // 1024 f32
  float* b1 = b0 + 1024;                               // 1024 f32

  const int total = 16 * 52 * 4 * 128 + 16 * 64 * 4 * 128 + 2048;
  pack_weights<<<(total + 255) / 256, 256, 0, stream>>>(
      Wih0, Whh0, bih0, bhh0, Wih1, Whh1, bih1, bhh1, W0p, W1p, b0, b1);
  lstm_fused<<<256, NTHREADS, 0, stream>>>(x, W0p, W1p, b0, b1, Wfc, bfc, out);
}

// Round 13
// 459.883 us; speedup vs baseline: 1.0371x; 1.0371x over previous
//
#include <hip/hip_runtime.h>

#define NTHREADS 512

typedef __attribute__((ext_vector_type(8))) short s16x8;
typedef __attribute__((ext_vector_type(4))) float f32x4;
typedef __attribute__((ext_vector_type(4))) unsigned int u32x4;

__device__ __forceinline__ unsigned short f2bf(float f) {
  unsigned u = __float_as_uint(f);
  u += 0x7fffu + ((u >> 16) & 1u);
  return (unsigned short)(u >> 16);
}
__device__ __forceinline__ float bf2f(unsigned short s) {
  return __uint_as_float(((unsigned)s) << 16);
}
__device__ __forceinline__ float sigm(float x) {
  return __builtin_amdgcn_rcpf(1.0f + __expf(-x));
}
__device__ __forceinline__ float tanh_fast(float x) {
  return 1.0f - 2.0f * __builtin_amdgcn_rcpf(1.0f + __expf(2.0f * x));
}
__device__ __forceinline__ f32x4 mfma_bf16(u32x4 a, u32x4 b, f32x4 c) {
  union { u32x4 u; s16x8 s; } ua, ub;
  ua.u = a; ub.u = b;
  return __builtin_amdgcn_mfma_f32_16x16x32_bf16(ua.s, ub.s, c, 0, 0, 0);
}

// ---------------- weight pre-pack ----------------
// [nb(16)][kb][g(4)][16 n][8 k], bf16.
//   W0p: kb in [0,52)  (k = kb*8: k<160 from W_ih0, else W_hh0)
//   W1p: kb in [0,64)  (k<256 from W_ih1, else W_hh1)
// b0/b1: b_ih+b_hh pre-summed, f32.
__global__ void pack_weights(const float* __restrict__ Wih0, const float* __restrict__ Whh0,
                             const float* __restrict__ bih0, const float* __restrict__ bhh0,
                             const float* __restrict__ Wih1, const float* __restrict__ Whh1,
                             const float* __restrict__ bih1, const float* __restrict__ bhh1,
                             unsigned short* __restrict__ W0p, unsigned short* __restrict__ W1p,
                             float* __restrict__ b0, float* __restrict__ b1) {
  int e = blockIdx.x * 256 + threadIdx.x;
  const int N0 = 16 * 52 * 4 * 128;   // 425984
  const int N1 = 16 * 64 * 4 * 128;   // 524288
  if (e < N0) {
    int kk = e & 7, t1 = e >> 3;
    int n = t1 & 15, t2 = t1 >> 4;
    int g = t2 & 3, t3 = t2 >> 2;
    int kb = t3 % 52, nb = t3 / 52;
    int gn = g * 256 + nb * 16 + n, k = kb * 8 + kk;
    float v = (k < 160) ? Wih0[gn * 160 + k] : Whh0[gn * 256 + (k - 160)];
    W0p[e] = f2bf(v);
  } else if (e < N0 + N1) {
    int e2 = e - N0;
    int kk = e2 & 7, t1 = e2 >> 3;
    int n = t1 & 15, t2 = t1 >> 4;
    int g = t2 & 3, t3 = t2 >> 2;
    int kb = t3 & 63, nb = t3 >> 6;
    int gn = g * 256 + nb * 16 + n, k = kb * 8 + kk;
    float v = (k < 256) ? Wih1[gn * 256 + k] : Whh1[gn * 256 + (k - 256)];
    W1p[e2] = f2bf(v);
  } else if (e < N0 + N1 + 1024) {
    int n = e - (N0 + N1);
    b0[n] = bih0[n] + bhh0[n];
  } else if (e < N0 + N1 + 2048) {
    int n = e - (N0 + N1 + 1024);
    b1[n] = bih1[n] + bhh1[n];
  }
}

// ---- rolled K-pass, reordered W prefetch (r9 = converged best) ----
// THE REGISTER WALL (6 confirmations: r3,r4,r5,r7,r10,r12-adjacent):
// unified file 256/wave at 2 waves/SIMD = acc(64)+c(64) acc-side + arch
// 128 = staging(64)+addr. Staging regs must not cross ANY phase boundary.
// Levers measured and closed: occupancy (L2-BW-bound, r3), deeper W
// rotation (spill, r4/r5), cross-phase prefetch (spill, r7/r10), barrier
// count (neutral, r8), wave specialization (-4.5%, r12). The one win:
//  1. Each W slot refilled IMMEDIATELY after the mfma16 that consumes it
//     (WAR-safe): W issue->use distance ~2.5 mfma16-blocks (~390-780 cyc)
//     — covers L2 latency under contention. (+6%: 374 -> 353 us)
//  2. The two K-segments of a pass are merged into ONE kloop with a
//     uniform A-pointer switch at group SW (W pipeline cold-starts
//     once per pass).
// Tail: for odd N the last b1 refill overreads 1 group (4 KB) past the
// stream — lands inside W1p / next stream, in-bounds of d_ws, never used.
__device__ __forceinline__ void ld4(u32x4 d[4], const u32x4* p) {
  d[0] = p[0]; d[1] = p[16]; d[2] = p[32]; d[3] = p[48];
}
__device__ __forceinline__ void mfma16(const u32x4 a[4], const u32x4 b[4],
                                       f32x4 acc[4][4]) {
#pragma unroll
  for (int g = 0; g < 4; g++)
#pragma unroll
    for (int rt = 0; rt < 4; rt++)
      acc[g][rt] = mfma_bf16(a[rt], b[g], acc[g][rt]);
}
template <int N, int SW>
__device__ __forceinline__ void kloop2(const u32x4* apX, const u32x4* apH,
                                       const u32x4* wp, f32x4 acc[4][4]) {
  u32x4 a0[4], b0[4], a1[4], b1[4];
  const u32x4* ap = apX;
  ld4(a0, ap); ap += 256;
  ld4(b0, wp); ld4(b1, wp + 256); wp += 512;
  int g = 1;  // next A group index to load
#pragma unroll 1
  for (int i = 0; i < (N - 2 + (N & 1)) / 2; i++) {
    if (g == SW) ap = apH;
    ld4(a1, ap); ap += 256; g++;        // A for group 2i+1 (dist 1)
    mfma16(a0, b0, acc);                // consume group 2i
    ld4(b0, wp); wp += 256;             // W refill -> group 2i+2 (dist ~2.5)
    if (g == SW) ap = apH;
    ld4(a0, ap); ap += 256; g++;        // A for group 2i+2
    mfma16(a1, b1, acc);                // consume group 2i+1
    ld4(b1, wp); wp += 256;             // W refill -> group 2i+3
  }
  if constexpr ((N & 1) == 0) {
    if (g == SW) ap = apH;
    ld4(a1, ap);                        // A for group N-1
    mfma16(a0, b0, acc);                // group N-2
    mfma16(a1, b1, acc);                // group N-1
  } else {
    mfma16(a0, b0, acc);                // group N-1
  }
}

// ---------------- fused 2-layer LSTM + FC ----------------
// 256 blocks x 512 threads; block owns 64 batch rows for all 10 steps.
// LDS 158 KB (1 blk/CU, 2 waves/SIMD); bf16 A-layout [kblk][row][8k].
// 2 barriers/step: x(t+1) staged inline before B3 (B3 = stage barrier).
// Layer0 pass: kloop2<13,5> (x-part 5 groups | h-part 8).
// Layer1 pass: kloop2<16,8> (h1_new 8 | h2_prev 8).
// c-state: rolled-jt A/B swap trick — static indices, reg-resident.
__global__ __attribute__((amdgpu_flat_work_group_size(NTHREADS, NTHREADS),
                          amdgpu_waves_per_eu(2, 2)))
void lstm_fused(const float* __restrict__ x,
                const unsigned short* __restrict__ W0p,
                const unsigned short* __restrict__ W1p,
                const float* __restrict__ b0,
                const float* __restrict__ b1,
                const float* __restrict__ Wfc,
                const float* __restrict__ bfc,
                float* __restrict__ out) {
  __shared__ unsigned int lds_x[20 * 64 * 4];   // 20480 B
  __shared__ unsigned int lds_h1[16384];        // 65536 B = 2 bufs x [32 kblk][64 row][8k]
  __shared__ unsigned int lds_h2[16384];        // 65536 B
  __shared__ float lds_red[512];                // 2048 B
  __shared__ float lds_b0[1024];                // 4096 B
  __shared__ float lds_b1[1024];                // 4096 B   total 161792 B

  const int tid = threadIdx.x;
  const int wave = tid >> 6;
  const int lane = tid & 63;
  const int l15 = lane & 15;
  const int quad = lane >> 4;
  const long rowg0 = (long)blockIdx.x * 64;

  for (int i = tid; i < 16384; i += NTHREADS) { lds_h1[i] = 0u; lds_h2[i] = 0u; }
  for (int i = tid; i < 1024; i += NTHREADS) { lds_b0[i] = b0[i]; lds_b1[i] = b1[i]; }

  // ---- prologue: stage x(0) -> lds_x ----
#pragma unroll
  for (int s = 0; s < 5; s++) {
    int p = tid + s * NTHREADS;          // 2560 f32x4 = 64 rows x 40 quads
    int row = p / 40;
    int kq = p - row * 40;
    const f32x4 v = __builtin_nontemporal_load(
        (const f32x4*)(x + (rowg0 + row) * 1600 + kq * 4));
    unsigned lo = (unsigned)f2bf(v[0]) | ((unsigned)f2bf(v[1]) << 16);
    unsigned hi = (unsigned)f2bf(v[2]) | ((unsigned)f2bf(v[3]) << 16);
    int base = (kq >> 1) * 256 + row * 4 + (kq & 1) * 2;
    lds_x[base] = lo;
    lds_x[base + 1] = hi;
  }

  // persistent c-state: cA = state for the jt about to be processed,
  // cB = the other jt; swapped with static reg moves each jt iteration.
  float c0A[4][4], c0B[4][4], c2A[4][4], c2B[4][4];
#pragma unroll
  for (int rt = 0; rt < 4; rt++)
#pragma unroll
    for (int r = 0; r < 4; r++) {
      c0A[rt][r] = 0.f; c0B[rt][r] = 0.f;
      c2A[rt][r] = 0.f; c2B[rt][r] = 0.f;
    }
  float fc_acc = 0.0f;

  const u32x4* lxs = (const u32x4*)lds_x;
  const u32x4* lh1 = (const u32x4*)lds_h1;
  const u32x4* lh2 = (const u32x4*)lds_h2;
  unsigned short* lh1s = (unsigned short*)lds_h1;
  unsigned short* lh2s = (unsigned short*)lds_h2;
  const u32x4* w0q = (const u32x4*)W0p;
  const u32x4* w1q = (const u32x4*)W1p;

  __syncthreads();  // B0: zeros + biases + x(0) staged

  for (int t = 0; t < 10; t++) {
    const int rd = t & 1;        // prev-h buffer
    const int wr = rd ^ 1;       // new-h buffer

    // ======== layer 0: K=416 ([x_t | h1_prev]), 13 groups, switch@5 ========
#pragma unroll 1
    for (int jt = 0; jt < 2; jt++) {
      const int nbb = wave * 2 + jt;
      f32x4 acc[4][4];
#pragma unroll
      for (int g = 0; g < 4; g++)
#pragma unroll
        for (int rt = 0; rt < 4; rt++) acc[g][rt] = (f32x4){0.f, 0.f, 0.f, 0.f};

      kloop2<13, 5>(lxs + quad * 64 + l15,
                    lh1 + rd * 2048 + quad * 64 + l15,
                    w0q + (nbb * 52 + quad) * 64 + l15, acc);

      float b_i = lds_b0[0 * 256 + wave * 32 + jt * 16 + l15];
      float b_f = lds_b0[1 * 256 + wave * 32 + jt * 16 + l15];
      float b_g = lds_b0[2 * 256 + wave * 32 + jt * 16 + l15];
      float b_o = lds_b0[3 * 256 + wave * 32 + jt * 16 + l15];
#pragma unroll
      for (int rt = 0; rt < 4; rt++)
#pragma unroll
        for (int r = 0; r < 4; r++) {
          float iv = sigm(acc[0][rt][r] + b_i);
          float fv = sigm(acc[1][rt][r] + b_f);
          float gv = tanh_fast(acc[2][rt][r] + b_g);
          float ov = sigm(acc[3][rt][r] + b_o);
          float cn = fv * c0A[rt][r] + iv * gv;
          c0A[rt][r] = cn;
          int row = rt * 16 + quad * 4 + r;
          int col = wave * 32 + jt * 16 + l15;
          lh1s[wr * 16384 + ((col >> 3) * 64 + row) * 8 + (col & 7)] =
              f2bf(ov * tanh_fast(cn));
        }
      // swap cA <-> cB (static register moves)
#pragma unroll
      for (int rt = 0; rt < 4; rt++)
#pragma unroll
        for (int r = 0; r < 4; r++) {
          float tmp = c0A[rt][r]; c0A[rt][r] = c0B[rt][r]; c0B[rt][r] = tmp;
        }
    }
    __syncthreads();  // B2: h1[wr] complete; lds_x reads done

    // ======== layer 1: K=512 ([h1_new | h2_prev]), 16 groups, switch@8 ========
#pragma unroll 1
    for (int jt = 0; jt < 2; jt++) {
      const int nbb = wave * 2 + jt;
      f32x4 acc[4][4];
#pragma unroll
      for (int g = 0; g < 4; g++)
#pragma unroll
        for (int rt = 0; rt < 4; rt++) acc[g][rt] = (f32x4){0.f, 0.f, 0.f, 0.f};

      kloop2<16, 8>(lh1 + wr * 2048 + quad * 64 + l15,
                    lh2 + rd * 2048 + quad * 64 + l15,
                    w1q + (nbb * 64 + quad) * 64 + l15, acc);

      float b_i = lds_b1[0 * 256 + wave * 32 + jt * 16 + l15];
      float b_f = lds_b1[1 * 256 + wave * 32 + jt * 16 + l15];
      float b_g = lds_b1[2 * 256 + wave * 32 + jt * 16 + l15];
      float b_o = lds_b1[3 * 256 + wave * 32 + jt * 16 + l15];
#pragma unroll
      for (int rt = 0; rt < 4; rt++)
#pragma unroll
        for (int r = 0; r < 4; r++) {
          float iv = sigm(acc[0][rt][r] + b_i);
          float fv = sigm(acc[1][rt][r] + b_f);
          float gv = tanh_fast(acc[2][rt][r] + b_g);
          float ov = sigm(acc[3][rt][r] + b_o);
          float cn = fv * c2A[rt][r] + iv * gv;
          c2A[rt][r] = cn;
          int row = rt * 16 + quad * 4 + r;
          int col = wave * 32 + jt * 16 + l15;
          lh2s[wr * 16384 + ((col >> 3) * 64 + row) * 8 + (col & 7)] =
              f2bf(ov * tanh_fast(cn));
        }
      // swap cA <-> cB
#pragma unroll
      for (int rt = 0; rt < 4; rt++)
#pragma unroll
        for (int r = 0; r < 4; r++) {
          float tmp = c2A[rt][r]; c2A[rt][r] = c2B[rt][r]; c2B[rt][r] = tmp;
        }
    }

    // ---- stage x(t+1) -> lds_x, inline tight block (B3 = stage barrier) ----
    if (t < 9) {
#pragma unroll
      for (int s = 0; s < 5; s++) {
        int p = tid + s * NTHREADS;
        int row = p / 40;
        int kq = p - row * 40;
        const f32x4 v = __builtin_nontemporal_load(
            (const f32x4*)(x + (rowg0 + row) * 1600 + (t + 1) * 160 + kq * 4));
        unsigned lo = (unsigned)f2bf(v[0]) | ((unsigned)f2bf(v[1]) << 16);
        unsigned hi = (unsigned)f2bf(v[2]) | ((unsigned)f2bf(v[3]) << 16);
        int base = (kq >> 1) * 256 + row * 4 + (kq & 1) * 2;
        lds_x[base] = lo;
        lds_x[base + 1] = hi;
      }
    }
    __syncthreads();  // B3: h2[wr] complete + x(t+1) staged

    // ---- FC partial: logit += W_fc[t*256 + j] * h2_new[row][j] ----
    // (overlaps next step's L0 — touches only lh2[wr] and registers)
    {
      int row = tid >> 3;
      int jq = (tid & 7) * 32;
      float s = 0.f;
#pragma unroll
      for (int kb = 0; kb < 4; kb++) {
        u32x4 hv = lh2[wr * 2048 + ((jq >> 3) + kb) * 64 + row];
        const f32x4 wA = *(const f32x4*)(Wfc + t * 256 + jq + kb * 8);
        const f32x4 wB = *(const f32x4*)(Wfc + t * 256 + jq + kb * 8 + 4);
#pragma unroll
        for (int e = 0; e < 2; e++) {
          unsigned u = hv[e];
          s += bf2f((unsigned short)(u & 0xffffu)) * wA[2 * e];
          s += bf2f((unsigned short)(u >> 16)) * wA[2 * e + 1];
        }
#pragma unroll
        for (int e = 0; e < 2; e++) {
          unsigned u = hv[2 + e];
          s += bf2f((unsigned short)(u & 0xffffu)) * wB[2 * e];
          s += bf2f((unsigned short)(u >> 16)) * wB[2 * e + 1];
        }
      }
      fc_acc += s;
    }
  }

  lds_red[tid] = fc_acc;  // [row(64)][slot(8)]
  __syncthreads();
  if (tid < 64) {
    float s = 0.f;
#pragma unroll
    for (int e = 0; e < 8; e++) s += lds_red[tid * 8 + e];
    out[rowg0 + tid] = sigm(s + bfc[0]);
  }
}

extern "C" void kernel_launch(void* const* d_in, const int* in_sizes, int n_in,
                              void* d_out, int out_size, void* d_ws, size_t ws_size,
                              hipStream_t stream) {
  const float* x    = (const float*)d_in[0];
  const float* Wih0 = (const float*)d_in[1];
  const float* Whh0 = (const float*)d_in[2];
  const float* bih0 = (const float*)d_in[3];
  const float* bhh0 = (const float*)d_in[4];
  const float* Wih1 = (const float*)d_in[5];
  const float* Whh1 = (const float*)d_in[6];
  const float* bih1 = (const float*)d_in[7];
  const float* bhh1 = (const float*)d_in[8];
  const float* Wfc  = (const float*)d_in[9];
  const float* bfc  = (const float*)d_in[10];
  float* out = (float*)d_out;

  unsigned short* W0p = (unsigned short*)d_ws;         // 425984 bf16
  unsigned short* W1p = W0p + 16 * 52 * 4 * 128;       // 524288 bf16
  float* b0 = (float*)(W1p + 16 * 64 * 4 * 128);       // 1024 f32
  float* b1 = b0 + 1024;                               // 1024 f32

  const int total = 16 * 52 * 4 * 128 + 16 * 64 * 4 * 128 + 2048;
  pack_weights<<<(total + 255) / 256, 256, 0, stream>>>(
      Wih0, Whh0, bih0, bhh0, Wih1, Whh1, bih1, bhh1, W0p, W1p, b0, b1);
  lstm_fused<<<256, NTHREADS, 0, stream>>>(x, W0p, W1p, b0, b1, Wfc, bfc, out);
}